// Round 18
// baseline (21.216 us; speedup 1.0000x reference)
//
#include <hip/hip_runtime.h>

#define HH 128
#define WW 192
#define HW (HH * WW)

typedef float f32x4 __attribute__((ext_vector_type(4)));
typedef float f32x2v __attribute__((ext_vector_type(2)));
typedef __fp16 h2 __attribute__((ext_vector_type(2)));

__device__ __forceinline__ float relu(float v) { return fmaxf(v, 0.0f); }
__device__ __forceinline__ float fdot2(h2 a, h2 b, float c) {
    return __builtin_amdgcn_fdot2(a, b, c, false);
}
__device__ __forceinline__ h2 pkrtz(float a, float b) {
    return __builtin_amdgcn_cvt_pkrtz(a, b);
}
__device__ __forceinline__ h2 prelu2(h2 v) {
    h2 z = {(__fp16)0.0f, (__fp16)0.0f};
    return __builtin_elementwise_max(v, z);
}

// LDS packed-weight layout:
//   sWp (h2): [0..31] w0feat o*4+p=(w0[o][2+2p],w0[o][3+2p])
//             [32..63] w1 32+o*4+p=(w1[o][2p],w1[o][2p+1])
//             [64..67] w2 64+p=(w2[2p],w2[2p+1])
//   sF (f32): [0..7] w0x [8..15] w0y [16..23] b0 [24..31] b1 [32] b2

// 256-thread blocks: 1536 blocks all resident (6 blocks/CU, single dispatch
// round) vs 512t's 1.5 rounds -- kills the residency tail R16 exposed.

__global__ __launch_bounds__(256) void dmh_kernel(
    const float* __restrict__ mask_feats,   // (4,8,128,192)
    const float* __restrict__ params,       // (128,169)
    const float* __restrict__ locs,         // (128,2)
    const float* __restrict__ soi,          // (5,)
    const int*   __restrict__ im_inds,      // (128,)
    const int*   __restrict__ fpn_levels,   // (128,)
    const int*   __restrict__ stride_p,     // scalar (=8)
    float*       __restrict__ out)          // (128,1,256,384)
{
    const int tid = threadIdx.x;
    const int c0 = blockIdx.x * 64;   // source col tile origin
    const int r0 = blockIdx.y * 32;   // source row tile origin
    const int n  = blockIdx.z;        // instance

    __shared__ h2    sWp[68];
    __shared__ float sF[33];
    __shared__ float tile[33 * 66];   // rows -1..31 -> 0..32, cols -1..63 -> 0..64

    // ---- stage weights: fp16-pack matmul weights, fp32 for coords/biases ----
    if (tid < 169) {
        float v = params[(size_t)n * 169 + tid];
        __fp16* sWh = reinterpret_cast<__fp16*>(sWp);
        if (tid < 80) {
            int o = tid / 10, k = tid - o * 10;
            if (k == 0)      sF[o] = v;
            else if (k == 1) sF[8 + o] = v;
            else { int f = k - 2; sWh[(o * 4 + (f >> 1)) * 2 + (f & 1)] = (__fp16)v; }
        } else if (tid < 144) {
            int t = tid - 80, o = t >> 3, i = t & 7;
            sWh[(32 + o * 4 + (i >> 1)) * 2 + (i & 1)] = (__fp16)v;
        } else if (tid < 152) {
            int o = tid - 144;
            sWh[(64 + (o >> 1)) * 2 + (o & 1)] = (__fp16)v;
        } else if (tid < 160) sF[16 + (tid - 152)] = v;   // b0
        else if (tid < 168)   sF[24 + (tid - 160)] = v;   // b1
        else                  sF[32] = v;                  // b2
    }

    const int   stride = *stride_p;                 // 8
    const float half_s = 0.5f * (float)stride;      // 4.0
    const float locx = locs[2 * n + 0];
    const float locy = locs[2 * n + 1];
    const float inv  = 1.0f / soi[fpn_levels[n]];
    const float* fb  = mask_feats + (size_t)im_inds[n] * 8 * HW;

    // ---- interior geometry: 1 row x 8 cols per thread (two 4-px chunks) ----
    const int ir = tid >> 3;          // 0..31
    const int ic = (tid & 7) << 3;    // 0,8,...,56
    const int rr = r0 + ir, cc = c0 + ic;
    const float* fp = fb + rr * WW + cc;

    // chunk-A feat loads issued BEFORE the staging barrier
    f32x4 xvA[8];
    #pragma unroll
    for (int ch = 0; ch < 8; ++ch)
        xvA[ch] = *reinterpret_cast<const f32x4*>(fp + ch * HW);

    __syncthreads();

    // chunk-B loads issued now; latency hides under chunk-A compute
    f32x4 xvB[8];
    #pragma unroll
    for (int ch = 0; ch < 8; ++ch)
        xvB[ch] = *reinterpret_cast<const f32x4*>(fp + ch * HW + 4);

    const float rxd = -(float)stride * inv;
    const float ry  = (locy - (float)(rr * stride) - half_s) * inv;

    // hoisted layer-0 row term (shared by both chunks: same source row)
    float tO[8];
    #pragma unroll
    for (int o = 0; o < 8; ++o)
        tO[o] = fmaf(sF[8 + o], ry, sF[16 + o]);

    // ---- 4-px MLP chunk (cols colg..colg+3 -> tile cols tcol..tcol+3) ----
    auto mlp4 = [&](const f32x4* xv, int colg, int tcol) {
        float rx[4];
        rx[0] = (locx - (float)(colg * stride) - half_s) * inv;
        rx[1] = rx[0] + rxd; rx[2] = rx[1] + rxd; rx[3] = rx[2] + rxd;

        h2 xp[4][4];
        #pragma unroll
        for (int p = 0; p < 4; ++p)
            #pragma unroll
            for (int j = 0; j < 4; ++j)
                xp[p][j] = pkrtz(xv[2 * p][j], xv[2 * p + 1][j]);

        float h[8][4];
        #pragma unroll
        for (int o = 0; o < 8; ++o) {
            const h2 w0 = sWp[o * 4 + 0], w1 = sWp[o * 4 + 1],
                     w2 = sWp[o * 4 + 2], w3 = sWp[o * 4 + 3];
            float wx = sF[o];
            #pragma unroll
            for (int j = 0; j < 4; ++j) {
                float acc = fmaf(wx, rx[j], tO[o]);
                acc = fdot2(w0, xp[0][j], acc);
                acc = fdot2(w1, xp[1][j], acc);
                acc = fdot2(w2, xp[2][j], acc);
                acc = fdot2(w3, xp[3][j], acc);
                h[o][j] = acc;
            }
        }

        h2 hp[4][4];
        #pragma unroll
        for (int p = 0; p < 4; ++p)
            #pragma unroll
            for (int j = 0; j < 4; ++j)
                hp[p][j] = prelu2(pkrtz(h[2 * p][j], h[2 * p + 1][j]));

        float a[8][4];
        #pragma unroll
        for (int o = 0; o < 8; ++o) {
            const h2 w0 = sWp[32 + o * 4 + 0], w1 = sWp[32 + o * 4 + 1],
                     w2 = sWp[32 + o * 4 + 2], w3 = sWp[32 + o * 4 + 3];
            float b1 = sF[24 + o];
            #pragma unroll
            for (int j = 0; j < 4; ++j) {
                float acc = b1;
                acc = fdot2(w0, hp[0][j], acc);
                acc = fdot2(w1, hp[1][j], acc);
                acc = fdot2(w2, hp[2][j], acc);
                acc = fdot2(w3, hp[3][j], acc);
                a[o][j] = acc;
            }
        }

        const h2 v0 = sWp[64], v1 = sWp[65], v2 = sWp[66], v3 = sWp[67];
        const float b2v = sF[32];
        #pragma unroll
        for (int j = 0; j < 4; ++j) {
            h2 a0 = prelu2(pkrtz(a[0][j], a[1][j]));
            h2 a1 = prelu2(pkrtz(a[2][j], a[3][j]));
            h2 a2 = prelu2(pkrtz(a[4][j], a[5][j]));
            h2 a3 = prelu2(pkrtz(a[6][j], a[7][j]));
            float lg = b2v;
            lg = fdot2(v0, a0, lg);
            lg = fdot2(v1, a1, lg);
            lg = fdot2(v2, a2, lg);
            lg = fdot2(v3, a3, lg);
            tile[(ir + 1) * 66 + tcol + j] = lg;
        }
    };

    mlp4(xvA, cc, ic + 1);
    mlp4(xvB, cc + 4, ic + 5);

    // ---------- phase 1b: 97 halo px, same fp16-dot2 math, 1 px ----------
    if (tid < 97) {
        int r, c;
        if (tid < 65) { r = -1; c = tid - 1; }      // row -1, cols -1..63
        else          { r = tid - 65; c = -1; }     // rows 0..31, col -1
        int hr = min(max(r0 + r, 0), HH - 1);
        int hc = min(max(c0 + c, 0), WW - 1);
        const float* hfp = fb + hr * WW + hc;
        float rx  = (locx - (float)(hc * stride) - half_s) * inv;
        float ry2 = (locy - (float)(hr * stride) - half_s) * inv;
        h2 xp[4];
        #pragma unroll
        for (int p = 0; p < 4; ++p)
            xp[p] = pkrtz(hfp[(2 * p) * HW], hfp[(2 * p + 1) * HW]);
        float hh[8];
        #pragma unroll
        for (int o = 0; o < 8; ++o) {
            float acc = fmaf(sF[o], rx, fmaf(sF[8 + o], ry2, sF[16 + o]));
            #pragma unroll
            for (int p = 0; p < 4; ++p) acc = fdot2(sWp[o * 4 + p], xp[p], acc);
            hh[o] = acc;
        }
        h2 hp[4];
        #pragma unroll
        for (int p = 0; p < 4; ++p)
            hp[p] = prelu2(pkrtz(hh[2 * p], hh[2 * p + 1]));
        float aa[8];
        #pragma unroll
        for (int o = 0; o < 8; ++o) {
            float acc = sF[24 + o];
            #pragma unroll
            for (int p = 0; p < 4; ++p) acc = fdot2(sWp[32 + o * 4 + p], hp[p], acc);
            aa[o] = acc;
        }
        float lg = sF[32];
        #pragma unroll
        for (int p = 0; p < 4; ++p) {
            h2 ap = prelu2(pkrtz(aa[2 * p], aa[2 * p + 1]));
            lg = fdot2(sWp[64 + p], ap, lg);
        }
        tile[(r + 1) * 66 + (c + 1)] = lg;
    }
    __syncthreads();

    // ---------- phase 2: x2 aligned upsample, conflict-free ----------
    // wave wv (0..3) owns 16 output rows, uniform tile row per iteration;
    // lane k reads tile cols k,k+1 (stride-1 = free 2-way alias), 8B stores.
    {
        const int lane = tid & 63;
        const int wv   = tid >> 6;        // 0..3
        float* ob = out + ((size_t)n * 256 + 2 * r0) * 384 + 2 * c0 + 2 * lane;
        #pragma unroll
        for (int i = 0; i < 16; ++i) {
            int yt  = wv * 16 + i;        // 0..63
            int iy  = yt - 1;
            int fy  = iy & 1;
            int sr  = (iy >> 1) + 1;      // tile row 0..32 (arith shift: yt=0 -> 0)
            const float* ta = &tile[sr * 66 + lane];
            float t0, t1;
            if (fy) {
                const float* tb = ta + 66;
                t0 = 0.5f * (ta[0] + tb[0]);
                t1 = 0.5f * (ta[1] + tb[1]);
            } else {
                t0 = ta[0];
                t1 = ta[1];
            }
            f32x2v o2 = {0.5f * (t0 + t1), t1};
            __builtin_nontemporal_store(o2,
                reinterpret_cast<f32x2v*>(ob + (size_t)yt * 384));
        }
    }
}

extern "C" void kernel_launch(void* const* d_in, const int* in_sizes, int n_in,
                              void* d_out, int out_size, void* d_ws, size_t ws_size,
                              hipStream_t stream) {
    const float* mask_feats = (const float*)d_in[0];
    const float* params     = (const float*)d_in[1];
    const float* locs       = (const float*)d_in[2];
    const float* soi        = (const float*)d_in[3];
    const int*   im_inds    = (const int*)d_in[4];
    const int*   fpn_levels = (const int*)d_in[5];
    const int*   stride_p   = (const int*)d_in[6];
    float* out = (float*)d_out;

    dim3 grid(WW / 64, HH / 32, 128);   // (3, 4, 128) = 1536 blocks, all resident
    dim3 block(256);
    dmh_kernel<<<grid, block, 0, stream>>>(
        mask_feats, params, locs, soi, im_inds, fpn_levels, stride_p, out);
}